// Round 7
// baseline (98.661 us; speedup 1.0000x reference)
//
#include <hip/hip_runtime.h>

// Problem constants
#define N_FILTERS 1024
#define B_TOTAL   1024
#define IMG       64            // H = W = 64
#define PAD_DIM   70            // 64 + 2*3 padded image side
// Xt layout in d_ws: fp16 [8 bg][PAD_DIM*PAD_DIM pixels][128 batches]  (10 MB).
// bg-major: each XCD's hot slice (4900 px * 256 B = 1.25 MB) is CONTIGUOUS and
// pixel stride is 256 B, so the 10 column loads per window row fold into
// 13-bit immediate offsets (wc*256 <= 2304).
//
// LESSONS:
//  r1-r2: __launch_bounds__ min-waves on gfx950 caps VGPRs at ~256/min_waves
//         -> (256,4)=64, (256,6)=40; spills 60-145 MB. Don't use min-waves.
//  r3:    one-batch-per-lane lost v_pk_fma_f32 packing (2x issue cost).
//  r5:    packed + lazy-init + early-fold: dur 97.55 (best). filters ~27us
//         vs ~9us issue floor.
//  r6:    source-level 3-buffer prefetch NEUTRAL -> compiler's vmcnt placement
//         (not prefetch distance) is the stall; it re-drains per row because
//         buffers rotate through the same registers.
//  r7:    inline-asm loads + counted s_waitcnt vmcnt(10) + sched_barrier(0)
//         (rule #18) = manual software pipeline. Math identical to r5.
//  fixed: harness re-poisons the 256 MiB workspace every iter (~45 us fill)
//         + launch/graph overhead; non-filters total ~70 us (anchored on r2).

typedef _Float16 half2_t __attribute__((ext_vector_type(2)));
typedef float    fvec2  __attribute__((ext_vector_type(2)));

// ---------------- prep: transpose + border-zero fused in one launch ----------------
// Blocks 0..1023: transpose X [1024 b][4096 p] -> Xt fp16 bg-major.
// Blocks 1024..1827: zero one border pixel each (804 px * 8 bg * 256 B).
__global__ __launch_bounds__(256) void prep_kernel(
    const float* __restrict__ X, _Float16* __restrict__ Xt)
{
    const int bid = blockIdx.x;
    if (bid >= 1024) {
        int pb = bid - 1024;              // 0..803
        int r, c;
        if (pb < 420) {
            int r6 = pb / 70;             // 0..5
            c = pb - r6 * 70;
            r = (r6 < 3) ? r6 : r6 + 64;  // rows 0,1,2,67,68,69
        } else {
            int q = pb - 420;
            r = 3 + q / 6;
            int k = q - (q / 6) * 6;      // 0..5
            c = (k < 3) ? k : k + 64;     // cols 0,1,2,67,68,69
        }
        const size_t pp = (size_t)r * PAD_DIM + c;
        const int bg = threadIdx.x >> 5, l = threadIdx.x & 31;
        unsigned long long* qp = (unsigned long long*)Xt
            + (size_t)bg * (4900ull * 32) + pp * 32 + l;
        *qp = 0ull;
        return;
    }

    __shared__ float T[64 * 65];         // [b_local][p_local], stride 65 kills conflicts
    const int pt = bid & 63;             // pixel tile (64 pixels)
    const int bt = bid >> 6;             // batch tile (64 batches)
    const int tx = threadIdx.x & 63, ty = threadIdx.x >> 6;

    #pragma unroll
    for (int pass = 0; pass < 16; ++pass) {
        int bl = pass * 4 + ty;          // lanes: consecutive pixels -> coalesced read
        T[bl * 65 + tx] = X[(size_t)(bt * 64 + bl) * 4096 + pt * 64 + tx];
    }
    __syncthreads();

    // write half2 (two consecutive batches) per lane -> dword stores, 8 passes
    const int h = threadIdx.x & 31;      // half2 index: batches 2h, 2h+1 of this 64-tile
    const int v = threadIdx.x >> 5;      // pixel sub-row 0..7
    half2_t* Xt2 = (half2_t*)Xt;
    #pragma unroll
    for (int pass = 0; pass < 8; ++pass) {
        int pl = pass * 8 + v;
        int p  = pt * 64 + pl;
        int r  = p >> 6, c = p & 63;
        half2_t val;
        val.x = (_Float16)T[(2 * h) * 65 + pl];
        val.y = (_Float16)T[(2 * h + 1) * 65 + pl];
        // batch b = bt*64 + 2h -> slice bg = bt>>1, half2 idx (bt&1)*32 + h
        Xt2[((size_t)(bt >> 1) * 4900 + (size_t)(r + 3) * PAD_DIM + (c + 3)) * 64
            + (bt & 1) * 32 + h] = val;
    }
}

// ---------------- main: 2 batches/lane, manual vmcnt-counted pipeline ----------------
// Block = 4 waves = 4 filters, 128 batches (2/lane). Grid 2048: bg = bid&7 pins
// the XCD slice. acc row y first written at wr==y (lazy init); conv row fy folds
// into pmax at wr==fy+4 and dies -> peak live acc rows = 5.
// Loads are inline-asm global_load_dword; before consuming row k we wait
// vmcnt(10) (row k+1's 10 loads remain in flight) -- the counted-wait pipeline
// the compiler won't emit on its own (r6 evidence). sched_barrier(0) after each
// waitcnt stops VALU consumers from being hoisted above it (rule #18).

#define LOAD_ROW_ASM(buf, WR) do {                                              \
    const half2_t* rp_ = Xg + (size_t)((si + (WR)) * PAD_DIM + sj) * 64;        \
    asm volatile("global_load_dword %0, %1, off"             : "=v"(buf[0]) : "v"(rp_)); \
    asm volatile("global_load_dword %0, %1, off offset:256"  : "=v"(buf[1]) : "v"(rp_)); \
    asm volatile("global_load_dword %0, %1, off offset:512"  : "=v"(buf[2]) : "v"(rp_)); \
    asm volatile("global_load_dword %0, %1, off offset:768"  : "=v"(buf[3]) : "v"(rp_)); \
    asm volatile("global_load_dword %0, %1, off offset:1024" : "=v"(buf[4]) : "v"(rp_)); \
    asm volatile("global_load_dword %0, %1, off offset:1280" : "=v"(buf[5]) : "v"(rp_)); \
    asm volatile("global_load_dword %0, %1, off offset:1536" : "=v"(buf[6]) : "v"(rp_)); \
    asm volatile("global_load_dword %0, %1, off offset:1792" : "=v"(buf[7]) : "v"(rp_)); \
    asm volatile("global_load_dword %0, %1, off offset:2048" : "=v"(buf[8]) : "v"(rp_)); \
    asm volatile("global_load_dword %0, %1, off offset:2304" : "=v"(buf[9]) : "v"(rp_)); \
} while (0)

#define WAIT_VM10 do {                                                          \
    asm volatile("s_waitcnt vmcnt(10)" ::: "memory");                           \
    __builtin_amdgcn_sched_barrier(0);                                          \
} while (0)

#define WAIT_VM0 do {                                                           \
    asm volatile("s_waitcnt vmcnt(0)" ::: "memory");                            \
    __builtin_amdgcn_sched_barrier(0);                                          \
} while (0)

#define COMPUTE_ROW(buf, WR) do {                                               \
    fvec2 in_[10];                                                              \
    _Pragma("unroll")                                                           \
    for (int wc = 0; wc < 10; ++wc) {                                           \
        in_[wc].x = (float)buf[wc].x;                                           \
        in_[wc].y = (float)buf[wc].y;                                           \
    }                                                                           \
    _Pragma("unroll")                                                           \
    for (int y = 0; y < 6; ++y) {                                               \
        if (y >= (((WR) > 4) ? ((WR) - 4) : 0) && y <= (WR)) {                  \
            _Pragma("unroll")                                                   \
            for (int x = 0; x < 6; ++x) {                                       \
                if (y == (WR)) {            /* first touch: kernel row 0 */     \
                    fvec2 s_ = wk[0] * in_[x];                                  \
                    _Pragma("unroll")                                           \
                    for (int c = 1; c < 5; ++c) s_ = wk[c] * in_[x + c] + s_;   \
                    acc[y * 6 + x] = s_;                                        \
                } else {                                                        \
                    const int rr = (WR) - y;                                    \
                    fvec2 s_ = acc[y * 6 + x];                                  \
                    _Pragma("unroll")                                           \
                    for (int c = 0; c < 5; ++c)                                 \
                        s_ = wk[rr * 5 + c] * in_[x + c] + s_;                  \
                    acc[y * 6 + x] = s_;                                        \
                }                                                               \
            }                                                                   \
        }                                                                       \
    }                                                                           \
    if ((WR) >= 4) {                        /* conv row fy is complete: fold */ \
        const int fy = (WR) - 4;                                                \
        _Pragma("unroll")                                                       \
        for (int px = 0; px < 2; ++px) {                                        \
            fvec2 a0 = acc[fy * 6 + 3 * px];                                    \
            fvec2 a1 = acc[fy * 6 + 3 * px + 1];                                \
            fvec2 a2 = acc[fy * 6 + 3 * px + 2];                                \
            fvec2 m_;                                                           \
            m_.x = fmaxf(fmaxf(a0.x, a1.x), a2.x);                              \
            m_.y = fmaxf(fmaxf(a0.y, a1.y), a2.y);                              \
            const int pi = ((fy >= 3) ? 2 : 0) + px;                            \
            if (fy == 0 || fy == 3) {       /* fresh pool cell, no init */      \
                pmax[pi] = m_;                                                  \
            } else {                                                            \
                pmax[pi].x = fmaxf(pmax[pi].x, m_.x);                           \
                pmax[pi].y = fmaxf(pmax[pi].y, m_.y);                           \
            }                                                                   \
        }                                                                       \
    }                                                                           \
} while (0)

__global__ __launch_bounds__(256) void filters_main(
    const half2_t* __restrict__ Xt2,   // [8 bg][4900 px][64 half2]
    const float*   __restrict__ W,     // [F][25]
    const float*   __restrict__ bias,  // [F]
    const int*     __restrict__ pos,   // [F][2]
    float4*        __restrict__ out4)  // [B][1024 float4]  (= [B][F*4] floats)
{
    const int t    = threadIdx.x;
    const int lane = t & 63;
    const int w    = t >> 6;                       // wave id 0..3
    const int bg   = blockIdx.x & 7;               // batch group (128 b) = XCD pin
    const int fg   = blockIdx.x >> 3;              // filter group (4 filters)

    const int f  = fg * 4 + w;
    const int sf = __builtin_amdgcn_readfirstlane(f);
    const int si = __builtin_amdgcn_readfirstlane(pos[2 * sf]);       // row i, 0..59
    const int sj = __builtin_amdgcn_readfirstlane(pos[2 * sf + 1]);   // col j, 0..59

    float wk[25];
    const float* wp = W + sf * 25;                 // scalar address -> s_load into SGPRs
    #pragma unroll
    for (int k = 0; k < 25; ++k) wk[k] = wp[k];
    const float bv = bias[sf];                     // scalar -> s_load

    // lane handles batches (2*lane, 2*lane+1) of slice bg: half2 index = lane
    const half2_t* Xg = Xt2 + (size_t)bg * (4900ull * 64) + lane;

    fvec2 acc[36];    // lazily initialized; peak live = 5 rows (30 fvec2)
    fvec2 pmax[4];    // lazily initialized at fy==0 / fy==3

    half2_t bufA[10], bufB[10];

    // ensure the asm loads are the ONLY outstanding vmcnt entries in the loop
    asm volatile("s_waitcnt vmcnt(0)" ::: "memory");

    LOAD_ROW_ASM(bufA, 0);
    LOAD_ROW_ASM(bufB, 1);
    WAIT_VM10;  COMPUTE_ROW(bufA, 0);  LOAD_ROW_ASM(bufA, 2);
    WAIT_VM10;  COMPUTE_ROW(bufB, 1);  LOAD_ROW_ASM(bufB, 3);
    WAIT_VM10;  COMPUTE_ROW(bufA, 2);  LOAD_ROW_ASM(bufA, 4);
    WAIT_VM10;  COMPUTE_ROW(bufB, 3);  LOAD_ROW_ASM(bufB, 5);
    WAIT_VM10;  COMPUTE_ROW(bufA, 4);  LOAD_ROW_ASM(bufA, 6);
    WAIT_VM10;  COMPUTE_ROW(bufB, 5);  LOAD_ROW_ASM(bufB, 7);
    WAIT_VM10;  COMPUTE_ROW(bufA, 6);  LOAD_ROW_ASM(bufA, 8);
    WAIT_VM10;  COMPUTE_ROW(bufB, 7);  LOAD_ROW_ASM(bufB, 9);
    WAIT_VM10;  COMPUTE_ROW(bufA, 8);
    WAIT_VM0;   COMPUTE_ROW(bufB, 9);

    // ---- epilogue: merge 4 waves' outputs into full 64 B stores via LDS ----
    __shared__ float S[4][128][5];                 // batch stride 5 -> conflict-light
    #pragma unroll
    for (int k = 0; k < 4; ++k) {
        S[w][2 * lane][k]     = pmax[k].x + bv;
        S[w][2 * lane + 1][k] = pmax[k].y + bv;
    }
    __syncthreads();

    // thread t -> filter-sub q = t&3, batch r0 = t>>2 (+64 on 2nd pass);
    // 4 consecutive lanes write one contiguous 64 B line out[b][fg*16..+15].
    const int q = t & 3, r0 = t >> 2;
    #pragma unroll
    for (int half = 0; half < 2; ++half) {
        const int b = r0 + half * 64;
        float4 val;
        val.x = S[q][b][0];
        val.y = S[q][b][1];
        val.z = S[q][b][2];
        val.w = S[q][b][3];
        out4[(size_t)(bg * 128 + b) * 1024 + fg * 4 + q] = val;
    }
}

extern "C" void kernel_launch(void* const* d_in, const int* in_sizes, int n_in,
                              void* d_out, int out_size, void* d_ws, size_t ws_size,
                              hipStream_t stream) {
    const float* X    = (const float*)d_in[0];
    const float* W    = (const float*)d_in[1];
    const float* bias = (const float*)d_in[2];
    const int*   pos  = (const int*)d_in[3];
    float4* out4 = (float4*)d_out;
    _Float16* Xt = (_Float16*)d_ws;        // 8*4900*128 fp16 = 10 MB

    prep_kernel<<<1024 + 804, 256, 0, stream>>>(X, Xt);
    filters_main<<<2048, 256, 0, stream>>>((const half2_t*)Xt, W, bias, pos, out4);
}

// Round 10
// 97.768 us; speedup vs baseline: 1.0091x; 1.0091x over previous
//
#include <hip/hip_runtime.h>

// Problem constants
#define N_FILTERS 1024
#define B_TOTAL   1024
#define IMG       64            // H = W = 64
#define PAD_DIM   70            // 64 + 2*3 padded image side
// Xt layout in d_ws: fp16 [8 bg][PAD_DIM*PAD_DIM pixels][128 batches]  (10 MB).
// bg-major: each XCD's hot slice (4900 px * 256 B = 1.25 MB) is CONTIGUOUS and
// pixel stride is 256 B, so the 10 column loads per window row fold into
// 13-bit immediate offsets (wc*256 <= 2304).
//
// LESSONS:
//  r1-r2: __launch_bounds__ min-waves on gfx950 caps VGPRs at ~256/min_waves
//         -> spills 60-145 MB. Don't use min-waves.
//  r3:    one-batch-per-lane lost v_pk_fma_f32 packing (2x issue cost).
//  r5:    packed + lazy-init + early-fold: 97.55 (best).
//  r6-r7: deeper prefetch AND hand-counted vmcnt(10) pipeline both NEUTRAL ->
//         filters_main is VALU-issue-bound near its ~8-10 us floor.
//         Budget: fill ~45 + resets/gaps ~30 + filters ~11 + prep ~11.
//  r8-r9: prep rewrite (float4 reads, 16B fp16 stores) hit "container failed
//         twice" on two consecutive submissions. Only novel construct vs all
//         passing kernels: ext_vector_type(8) _Float16 store. This round:
//         same structure, store via uint4 of bit-cast half2 pairs instead
//         (identical bytes/rounding, no 8-wide fp16 vector type).

typedef _Float16 half2_t __attribute__((ext_vector_type(2)));
typedef float    fvec2  __attribute__((ext_vector_type(2)));

__device__ __forceinline__ unsigned pack2(float a, float b) {
    half2_t h;
    h.x = (_Float16)a;                  // RTN, same as r5's scalar casts
    h.y = (_Float16)b;
    return __builtin_bit_cast(unsigned, h);
}

// ---------------- prep: transpose + border-zero fused in one launch ----------------
// Blocks 0..1023: transpose X [1024 b][4096 p] -> Xt fp16 bg-major.
//   read:  4 passes, each thread one float4 (row bl=16p+(t>>4), cols 4(t&15)..+3)
//   store: 2 passes, each thread 8 batches of one pixel as one 16 B dwordx4
// Blocks 1024..1827: zero one border pixel each (804 px * 8 bg * 256 B).
__global__ __launch_bounds__(256) void prep_kernel(
    const float* __restrict__ X, _Float16* __restrict__ Xt)
{
    const int bid = blockIdx.x;

    if (bid >= 1024) {
        int pb = bid - 1024;              // 0..803
        int r, c;
        if (pb < 420) {
            int r6 = pb / 70;             // 0..5
            c = pb - r6 * 70;
            r = (r6 < 3) ? r6 : r6 + 64;  // rows 0,1,2,67,68,69
        } else {
            int q = pb - 420;
            r = 3 + q / 6;
            int k = q - (q / 6) * 6;      // 0..5
            c = (k < 3) ? k : k + 64;     // cols 0,1,2,67,68,69
        }
        const size_t pp = (size_t)r * PAD_DIM + c;
        const int bg = threadIdx.x >> 5, l = threadIdx.x & 31;
        unsigned long long* qp = (unsigned long long*)Xt
            + (size_t)bg * (4900ull * 32) + pp * 32 + l;
        *qp = 0ull;
        return;
    }

    __shared__ float T[64 * 65];         // [b_local][p_local], stride 65: <=2-way banks
    const int pt = bid & 63;             // pixel tile (64 pixels)
    const int bt = bid >> 6;             // batch tile (64 batches)
    const int t  = threadIdx.x;

    // ---- read phase: 4 passes of float4 ----
    {
        const int r16 = t >> 4;          // row-within-pass 0..15
        const int c4  = (t & 15) * 4;    // pixel col 0,4,...,60
        #pragma unroll
        for (int p = 0; p < 4; ++p) {
            const int bl = p * 16 + r16; // local batch row 0..63
            const float4 v = *reinterpret_cast<const float4*>(
                X + (size_t)(bt * 64 + bl) * 4096 + pt * 64 + c4);
            T[bl * 65 + c4 + 0] = v.x;
            T[bl * 65 + c4 + 1] = v.y;
            T[bl * 65 + c4 + 2] = v.z;
            T[bl * 65 + c4 + 3] = v.w;
        }
    }
    __syncthreads();

    // ---- store phase: 2 passes, 8 batches (16 B) per thread per pass ----
    {
        const int lb = t & 7;            // batch octet 0..7 (local batches 8lb..8lb+7)
        #pragma unroll
        for (int p = 0; p < 2; ++p) {
            const int pl = p * 32 + (t >> 3);  // local pixel 0..63
            const int pg = pt * 64 + pl;       // global pixel 0..4095
            const int r  = pg >> 6, c = pg & 63;
            // LDS reads: bank = (8*lb + k + pl) % 32 -> 2-way across the wave
            uint4 vv;
            vv.x = pack2(T[(8 * lb + 0) * 65 + pl], T[(8 * lb + 1) * 65 + pl]);
            vv.y = pack2(T[(8 * lb + 2) * 65 + pl], T[(8 * lb + 3) * 65 + pl]);
            vv.z = pack2(T[(8 * lb + 4) * 65 + pl], T[(8 * lb + 5) * 65 + pl]);
            vv.w = pack2(T[(8 * lb + 6) * 65 + pl], T[(8 * lb + 7) * 65 + pl]);
            // slice bg = bt>>1; dword (half2) index (bt&1)*32 + 4*lb -> 16B-aligned
            unsigned* dst = (unsigned*)Xt
                + ((size_t)(bt >> 1) * 4900 + (size_t)(r + 3) * PAD_DIM + (c + 3)) * 64
                + (bt & 1) * 32 + lb * 4;
            *reinterpret_cast<uint4*>(dst) = vv;
        }
    }
}

// ---------------- main: 2 batches/lane (v_pk_fma_f32), early fold, lazy init ----------------
// r5 verbatim (best measured 97.55; r6/r7 pipeline variants neutral).
// Block = 4 waves = 4 filters, 128 batches (2/lane). Grid 2048: bg = bid&7 pins
// the XCD slice. acc row y first written at wr==y (lazy init); conv row fy folds
// into pmax at wr==fy+4 and dies -> peak live acc rows = 5.

#define LOAD_ROW(buf, WR) do {                                                  \
    const half2_t* rp_ = Xg + (size_t)((si + (WR)) * PAD_DIM + sj) * 64;        \
    _Pragma("unroll")                                                           \
    for (int wc = 0; wc < 10; ++wc) buf[wc] = rp_[wc * 64];                     \
} while (0)

#define COMPUTE_ROW(buf, WR) do {                                               \
    fvec2 in_[10];                                                              \
    _Pragma("unroll")                                                           \
    for (int wc = 0; wc < 10; ++wc) {                                           \
        in_[wc].x = (float)buf[wc].x;                                           \
        in_[wc].y = (float)buf[wc].y;                                           \
    }                                                                           \
    _Pragma("unroll")                                                           \
    for (int y = 0; y < 6; ++y) {                                               \
        if (y >= (((WR) > 4) ? ((WR) - 4) : 0) && y <= (WR)) {                  \
            _Pragma("unroll")                                                   \
            for (int x = 0; x < 6; ++x) {                                       \
                if (y == (WR)) {            /* first touch: kernel row 0 */     \
                    fvec2 s_ = wk[0] * in_[x];                                  \
                    _Pragma("unroll")                                           \
                    for (int c = 1; c < 5; ++c) s_ = wk[c] * in_[x + c] + s_;   \
                    acc[y * 6 + x] = s_;                                        \
                } else {                                                        \
                    const int rr = (WR) - y;                                    \
                    fvec2 s_ = acc[y * 6 + x];                                  \
                    _Pragma("unroll")                                           \
                    for (int c = 0; c < 5; ++c)                                 \
                        s_ = wk[rr * 5 + c] * in_[x + c] + s_;                  \
                    acc[y * 6 + x] = s_;                                        \
                }                                                               \
            }                                                                   \
        }                                                                       \
    }                                                                           \
    if ((WR) >= 4) {                        /* conv row fy is complete: fold */ \
        const int fy = (WR) - 4;                                                \
        _Pragma("unroll")                                                       \
        for (int px = 0; px < 2; ++px) {                                        \
            fvec2 a0 = acc[fy * 6 + 3 * px];                                    \
            fvec2 a1 = acc[fy * 6 + 3 * px + 1];                                \
            fvec2 a2 = acc[fy * 6 + 3 * px + 2];                                \
            fvec2 m_;                                                           \
            m_.x = fmaxf(fmaxf(a0.x, a1.x), a2.x);                              \
            m_.y = fmaxf(fmaxf(a0.y, a1.y), a2.y);                              \
            const int pi = ((fy >= 3) ? 2 : 0) + px;                            \
            if (fy == 0 || fy == 3) {       /* fresh pool cell, no init */      \
                pmax[pi] = m_;                                                  \
            } else {                                                            \
                pmax[pi].x = fmaxf(pmax[pi].x, m_.x);                           \
                pmax[pi].y = fmaxf(pmax[pi].y, m_.y);                           \
            }                                                                   \
        }                                                                       \
    }                                                                           \
} while (0)

__global__ __launch_bounds__(256) void filters_main(
    const half2_t* __restrict__ Xt2,   // [8 bg][4900 px][64 half2]
    const float*   __restrict__ W,     // [F][25]
    const float*   __restrict__ bias,  // [F]
    const int*     __restrict__ pos,   // [F][2]
    float4*        __restrict__ out4)  // [B][1024 float4]  (= [B][F*4] floats)
{
    const int t    = threadIdx.x;
    const int lane = t & 63;
    const int w    = t >> 6;                       // wave id 0..3
    const int bg   = blockIdx.x & 7;               // batch group (128 b) = XCD pin
    const int fg   = blockIdx.x >> 3;              // filter group (4 filters)

    const int f  = fg * 4 + w;
    const int sf = __builtin_amdgcn_readfirstlane(f);
    const int si = __builtin_amdgcn_readfirstlane(pos[2 * sf]);       // row i, 0..59
    const int sj = __builtin_amdgcn_readfirstlane(pos[2 * sf + 1]);   // col j, 0..59

    float wk[25];
    const float* wp = W + sf * 25;                 // scalar address -> s_load into SGPRs
    #pragma unroll
    for (int k = 0; k < 25; ++k) wk[k] = wp[k];

    // lane handles batches (2*lane, 2*lane+1) of slice bg: half2 index = lane
    const half2_t* Xg = Xt2 + (size_t)bg * (4900ull * 64) + lane;

    fvec2 acc[36];    // lazily initialized; peak live = 5 rows (30 fvec2)
    fvec2 pmax[4];    // lazily initialized at fy==0 / fy==3

    half2_t bufA[10], bufB[10];
    LOAD_ROW(bufA, 0);
    LOAD_ROW(bufB, 1);  COMPUTE_ROW(bufA, 0);
    LOAD_ROW(bufA, 2);  COMPUTE_ROW(bufB, 1);
    LOAD_ROW(bufB, 3);  COMPUTE_ROW(bufA, 2);
    LOAD_ROW(bufA, 4);  COMPUTE_ROW(bufB, 3);
    LOAD_ROW(bufB, 5);  COMPUTE_ROW(bufA, 4);
    LOAD_ROW(bufA, 6);  COMPUTE_ROW(bufB, 5);
    LOAD_ROW(bufB, 7);  COMPUTE_ROW(bufA, 6);
    LOAD_ROW(bufA, 8);  COMPUTE_ROW(bufB, 7);
    LOAD_ROW(bufB, 9);  COMPUTE_ROW(bufA, 8);
                        COMPUTE_ROW(bufB, 9);

    // ---- epilogue: merge 4 waves' outputs into full 64 B stores via LDS ----
    const float bv = bias[sf];
    __shared__ float S[4][128][5];                 // batch stride 5 -> conflict-light
    #pragma unroll
    for (int k = 0; k < 4; ++k) {
        S[w][2 * lane][k]     = pmax[k].x + bv;
        S[w][2 * lane + 1][k] = pmax[k].y + bv;
    }
    __syncthreads();

    // thread t -> filter-sub q = t&3, batch r0 = t>>2 (+64 on 2nd pass);
    // 4 consecutive lanes write one contiguous 64 B line out[b][fg*16..+15].
    const int q = t & 3, r0 = t >> 2;
    #pragma unroll
    for (int half = 0; half < 2; ++half) {
        const int b = r0 + half * 64;
        float4 val;
        val.x = S[q][b][0];
        val.y = S[q][b][1];
        val.z = S[q][b][2];
        val.w = S[q][b][3];
        out4[(size_t)(bg * 128 + b) * 1024 + fg * 4 + q] = val;
    }
}

extern "C" void kernel_launch(void* const* d_in, const int* in_sizes, int n_in,
                              void* d_out, int out_size, void* d_ws, size_t ws_size,
                              hipStream_t stream) {
    const float* X    = (const float*)d_in[0];
    const float* W    = (const float*)d_in[1];
    const float* bias = (const float*)d_in[2];
    const int*   pos  = (const int*)d_in[3];
    float4* out4 = (float4*)d_out;
    _Float16* Xt = (_Float16*)d_ws;        // 8*4900*128 fp16 = 10 MB

    prep_kernel<<<1024 + 804, 256, 0, stream>>>(X, Xt);
    filters_main<<<2048, 256, 0, stream>>>((const half2_t*)Xt, W, bias, pos, out4);
}